// Round 11
// baseline (389.253 us; speedup 1.0000x reference)
//
#include <hip/hip_runtime.h>
#include <stdint.h>

#define MROWS 8192   // B*S
#define DM    1024
#define NH    16
#define HD    64
#define SEQ   2048

typedef __bf16 bf16x8 __attribute__((ext_vector_type(8)));
typedef __bf16 bf16x4 __attribute__((ext_vector_type(4)));
typedef float  floatx4 __attribute__((ext_vector_type(4)));

// 0.125 (1/sqrt(64)) * log2(e): folded into Q so flash scores are already base-2
#define QSCALE 0.18033688011112042f

// T1 XCD-aware swizzle for 512-block grids (512 % 8 == 0 -> bijective):
// hardware slot bid runs logical tile (bid%8)*64 + bid/8, so each XCD gets 64
// CONSECUTIVE logical tiles -> blocks sharing an A-panel / K,V head sit on the
// same XCD's L2 instead of being round-robined across all 8.
__device__ __forceinline__ int xcd_swz512(int bid) {
  return ((bid & 7) << 6) | (bid >> 3);
}

__device__ __forceinline__ void async16(const void* g, void* l) {
  __builtin_amdgcn_global_load_lds(
      (__attribute__((address_space(1))) void*)g,
      (__attribute__((address_space(3))) void*)l,
      16, 0, 0);
}

__device__ __forceinline__ floatx4 mfma16(bf16x8 a, bf16x8 b, floatx4 c) {
  return __builtin_amdgcn_mfma_f32_16x16x32_bf16(a, b, c, 0, 0, 0);
}

// ---------------- conversion kernels ----------------

__global__ void __launch_bounds__(256) split_x_kernel(const float* __restrict__ x,
                                                      __bf16* __restrict__ xh,
                                                      __bf16* __restrict__ xl) {
  const int i = blockIdx.x * 256 + threadIdx.x;
  const float4 v = reinterpret_cast<const float4*>(x)[i];
  const float vv[4] = {v.x, v.y, v.z, v.w};
  bf16x4 H, L;
#pragma unroll
  for (int j = 0; j < 4; ++j) {
    const __bf16 h = (__bf16)vv[j];
    H[j] = h;
    L[j] = (__bf16)(vv[j] - (float)h);
  }
  reinterpret_cast<bf16x4*>(xh)[i] = H;
  reinterpret_cast<bf16x4*>(xl)[i] = L;
}

// All 4 weight transposes in one launch: W [K][N] fp32 -> W^T [N][K] bf16
// hi (+ lo for Wq/Wk). which = blockIdx.x>>10 selects the matrix.
__global__ void __launch_bounds__(256) wtrans4_kernel(
    const float* __restrict__ Wq, const float* __restrict__ Wk,
    const float* __restrict__ Wv, const float* __restrict__ Wf,
    __bf16* __restrict__ Tqh, __bf16* __restrict__ Tql,
    __bf16* __restrict__ Tkh, __bf16* __restrict__ Tkl,
    __bf16* __restrict__ Tvh, __bf16* __restrict__ Tfh) {
  const int which = blockIdx.x >> 10;
  const int blk = blockIdx.x & 1023;
  const float* W = (which == 0) ? Wq : (which == 1) ? Wk : (which == 2) ? Wv : Wf;
  __bf16* Th = (which == 0) ? Tqh : (which == 1) ? Tkh : (which == 2) ? Tvh : Tfh;
  __bf16* Tl = (which == 0) ? Tql : (which == 1) ? Tkl : (__bf16*)nullptr;

  __shared__ float t[32][33];
  const int tx = threadIdx.x & 31, ty = threadIdx.x >> 5;
  const int bx = blk & 31, by = blk >> 5;
#pragma unroll
  for (int j = 0; j < 4; ++j) {
    const int k = by * 32 + ty + j * 8;
    t[ty + j * 8][tx] = W[(size_t)k * DM + bx * 32 + tx];
  }
  __syncthreads();
#pragma unroll
  for (int j = 0; j < 4; ++j) {
    const int n = bx * 32 + ty + j * 8;
    const int k = by * 32 + tx;
    const float v = t[tx][ty + j * 8];
    const __bf16 h = (__bf16)v;
    Th[(size_t)n * DM + k] = h;
    if (Tl) Tl[(size_t)n * DM + k] = (__bf16)(v - (float)h);
  }
}

// ---------------- NT GEMM (1-term): C[M,N] = A[M,K] * B^T ----------------
// OUTMODE: 1 = fp32, 3 = bf16 transposed per-head with PERMUTED key order:
//   Vt[b,h,d, 64*(s/64) + tauinv(s%64)]
// tauinv(a) = (a&32) | ((a&12)<<1) | ((a&16)>>2) | (a&3).
// This makes the flash PV B-fragment lane-local: V LDS position p = 32ks+8q4+e
// holds actual key tau(p) = 16*(2ks+(e>>2)) + 4q4 + (e&3), exactly the key that
// lane (lm,q4) holds in its score register s2[2ks+(e>>2)][.][e&3].
// R11: double-buffered LDS + single-barrier prefetch pipeline (R3/R9 structure).
// Grid-limited to 2 blocks/CU either way, so the extra 16KB LDS is free; the
// per-iter vmcnt(0)+double-barrier drain of the 2-phase loop is removed.
template <int OUTMODE>
__global__ void __launch_bounds__(256) gemm_nt(const __bf16* __restrict__ Ah,
                                               const __bf16* __restrict__ Bh,
                                               void* __restrict__ C0) {
  __shared__ __align__(16) __bf16 sAh[2][128 * 32];
  __shared__ __align__(16) __bf16 sBh[2][128 * 32];

  const int tid = threadIdx.x;
  const int lid = xcd_swz512(blockIdx.x);
  const int bm = lid >> 3;
  const int bn = lid & 7;
  const int m0 = bm << 7, n0 = bn << 7;
  const int w = tid >> 6;
  const int lane = tid & 63;
  const int wm = (w >> 1) << 6;
  const int wn = (w & 1) << 6;
  const int lm = lane & 15;
  const int q4 = lane >> 4;

  floatx4 acc[4][4];
  const floatx4 fz = {0.f, 0.f, 0.f, 0.f};
#pragma unroll
  for (int i = 0; i < 4; ++i)
#pragma unroll
    for (int j = 0; j < 4; ++j) acc[i][j] = fz;

  const int c0 = tid, c1 = tid + 256;
  const int row0 = c0 >> 2, cc0 = (c0 & 3) ^ ((row0 >> 1) & 3);
  const int row1 = c1 >> 2, cc1 = (c1 & 3) ^ ((row1 >> 1) & 3);

  int offA[4], offB[4];
#pragma unroll
  for (int i = 0; i < 4; ++i) {
    const int ra = wm + i * 16 + lm;
    offA[i] = ra * 32 + ((q4 ^ ((ra >> 1) & 3)) << 3);
    const int rb = wn + i * 16 + lm;
    offB[i] = rb * 32 + ((q4 ^ ((rb >> 1) & 3)) << 3);
  }

  size_t ga0 = (size_t)(m0 + row0) * DM + cc0 * 8;
  size_t gb0 = (size_t)(n0 + row0) * DM + cc0 * 8;
  size_t ga1 = (size_t)(m0 + row1) * DM + cc1 * 8;
  size_t gb1 = (size_t)(n0 + row1) * DM + cc1 * 8;

  // prologue: stage tile 0 -> buf0
  async16(Ah + ga0, &sAh[0][c0 * 8]);
  async16(Bh + gb0, &sBh[0][c0 * 8]);
  async16(Ah + ga1, &sAh[0][c1 * 8]);
  async16(Bh + gb1, &sBh[0][c1 * 8]);
  ga0 += 32; gb0 += 32; ga1 += 32; gb1 += 32;

  for (int it = 0; it < 32; ++it) {
    const int cur = it & 1;
    asm volatile("s_waitcnt vmcnt(0)" ::: "memory");
    __builtin_amdgcn_s_barrier();
    __builtin_amdgcn_sched_barrier(0);
    if (it < 31) {
      const int nxt = cur ^ 1;
      async16(Ah + ga0, &sAh[nxt][c0 * 8]);
      async16(Bh + gb0, &sBh[nxt][c0 * 8]);
      async16(Ah + ga1, &sAh[nxt][c1 * 8]);
      async16(Bh + gb1, &sBh[nxt][c1 * 8]);
      ga0 += 32; gb0 += 32; ga1 += 32; gb1 += 32;
    }

    bf16x8 ah[4], bh[4];
#pragma unroll
    for (int i = 0; i < 4; ++i) {
      ah[i] = *(const bf16x8*)&sAh[cur][offA[i]];
      bh[i] = *(const bf16x8*)&sBh[cur][offB[i]];
    }
#pragma unroll
    for (int i = 0; i < 4; ++i)
#pragma unroll
      for (int j = 0; j < 4; ++j)
        acc[i][j] = mfma16(ah[i], bh[j], acc[i][j]);
    // no trailing barrier: next iteration's barrier protects buf[cur] from
    // being overwritten before all waves have finished reading it
  }

#pragma unroll
  for (int i = 0; i < 4; ++i) {
#pragma unroll
    for (int j = 0; j < 4; ++j) {
#pragma unroll
      for (int r = 0; r < 4; ++r) {
        const int gr = m0 + wm + i * 16 + q4 * 4 + r;
        const int gc = n0 + wn + j * 16 + lm;
        const float v = acc[i][j][r];
        if constexpr (OUTMODE == 1) {
          ((float*)C0)[(size_t)gr * DM + gc] = v;
        } else {
          const int bb = gr >> 11, ss = gr & 2047;
          const int s6 = ss & 63;
          const int sp = (ss & ~63) | (s6 & 32) | ((s6 & 12) << 1) |
                         ((s6 & 16) >> 2) | (s6 & 3);
          const int hh = gc >> 6, dd = gc & 63;
          ((__bf16*)C0)[(((size_t)(bb * NH + hh) << 6) + dd) * SEQ + sp] = (__bf16)v;
        }
      }
    }
  }
}

// ---------------- fused Q+K projection GEMM ----------------
// C_q = A*Bq^T (scaled by QSCALE, hi/lo split), C_k = A*Bk^T (hi/lo split).
// Shares A staging and A fragments across both outputs. 3-term hi/lo product.
// (dbuf would need 96KB -> 1 block/CU, the R3 neutral trade; kept 2-phase.)
__global__ void __launch_bounds__(256, 2) gemm_qk(const __bf16* __restrict__ Ah,
                                                  const __bf16* __restrict__ Al,
                                                  const __bf16* __restrict__ Bqh,
                                                  const __bf16* __restrict__ Bql,
                                                  const __bf16* __restrict__ Bkh,
                                                  const __bf16* __restrict__ Bkl,
                                                  __bf16* __restrict__ Qh,
                                                  __bf16* __restrict__ Ql,
                                                  __bf16* __restrict__ Kh,
                                                  __bf16* __restrict__ Kl) {
  __shared__ __align__(16) __bf16 sAh[128 * 32];
  __shared__ __align__(16) __bf16 sAl[128 * 32];
  __shared__ __align__(16) __bf16 sQh_[128 * 32];
  __shared__ __align__(16) __bf16 sQl_[128 * 32];
  __shared__ __align__(16) __bf16 sKh_[128 * 32];
  __shared__ __align__(16) __bf16 sKl_[128 * 32];

  const int tid = threadIdx.x;
  const int lid = xcd_swz512(blockIdx.x);
  const int bm = lid >> 3;
  const int bn = lid & 7;
  const int m0 = bm << 7, n0 = bn << 7;
  const int w = tid >> 6;
  const int lane = tid & 63;
  const int wm = (w >> 1) << 6;
  const int wn = (w & 1) << 6;
  const int lm = lane & 15;
  const int q4 = lane >> 4;

  floatx4 accq[4][4], acck[4][4];
  const floatx4 fz = {0.f, 0.f, 0.f, 0.f};
#pragma unroll
  for (int i = 0; i < 4; ++i)
#pragma unroll
    for (int j = 0; j < 4; ++j) { accq[i][j] = fz; acck[i][j] = fz; }

  const int c0 = tid, c1 = tid + 256;
  const int row0 = c0 >> 2, cc0 = (c0 & 3) ^ ((row0 >> 1) & 3);
  const int row1 = c1 >> 2, cc1 = (c1 & 3) ^ ((row1 >> 1) & 3);

  int offA[4], offB[4];
#pragma unroll
  for (int i = 0; i < 4; ++i) {
    const int ra = wm + i * 16 + lm;
    offA[i] = ra * 32 + ((q4 ^ ((ra >> 1) & 3)) << 3);
    const int rb = wn + i * 16 + lm;
    offB[i] = rb * 32 + ((q4 ^ ((rb >> 1) & 3)) << 3);
  }

  size_t ga0 = (size_t)(m0 + row0) * DM + cc0 * 8;
  size_t gb0 = (size_t)(n0 + row0) * DM + cc0 * 8;
  size_t ga1 = (size_t)(m0 + row1) * DM + cc1 * 8;
  size_t gb1 = (size_t)(n0 + row1) * DM + cc1 * 8;

  for (int it = 0; it < 32; ++it) {
    async16(Ah + ga0, &sAh[c0 * 8]);
    async16(Al + ga0, &sAl[c0 * 8]);
    async16(Ah + ga1, &sAh[c1 * 8]);
    async16(Al + ga1, &sAl[c1 * 8]);
    async16(Bqh + gb0, &sQh_[c0 * 8]);
    async16(Bql + gb0, &sQl_[c0 * 8]);
    async16(Bqh + gb1, &sQh_[c1 * 8]);
    async16(Bql + gb1, &sQl_[c1 * 8]);
    async16(Bkh + gb0, &sKh_[c0 * 8]);
    async16(Bkl + gb0, &sKl_[c0 * 8]);
    async16(Bkh + gb1, &sKh_[c1 * 8]);
    async16(Bkl + gb1, &sKl_[c1 * 8]);
    ga0 += 32; gb0 += 32; ga1 += 32; gb1 += 32;
    __syncthreads();

    bf16x8 ah[4], al[4];
#pragma unroll
    for (int i = 0; i < 4; ++i) {
      ah[i] = *(const bf16x8*)&sAh[offA[i]];
      al[i] = *(const bf16x8*)&sAl[offA[i]];
    }
    // Q phase
    {
      bf16x8 bh[4], bl[4];
#pragma unroll
      for (int j = 0; j < 4; ++j) {
        bh[j] = *(const bf16x8*)&sQh_[offB[j]];
        bl[j] = *(const bf16x8*)&sQl_[offB[j]];
      }
#pragma unroll
      for (int i = 0; i < 4; ++i)
#pragma unroll
        for (int j = 0; j < 4; ++j) {
          accq[i][j] = mfma16(ah[i], bh[j], accq[i][j]);
          accq[i][j] = mfma16(ah[i], bl[j], accq[i][j]);
          accq[i][j] = mfma16(al[i], bh[j], accq[i][j]);
        }
    }
    // K phase
    {
      bf16x8 bh[4], bl[4];
#pragma unroll
      for (int j = 0; j < 4; ++j) {
        bh[j] = *(const bf16x8*)&sKh_[offB[j]];
        bl[j] = *(const bf16x8*)&sKl_[offB[j]];
      }
#pragma unroll
      for (int i = 0; i < 4; ++i)
#pragma unroll
        for (int j = 0; j < 4; ++j) {
          acck[i][j] = mfma16(ah[i], bh[j], acck[i][j]);
          acck[i][j] = mfma16(ah[i], bl[j], acck[i][j]);
          acck[i][j] = mfma16(al[i], bh[j], acck[i][j]);
        }
    }
    __syncthreads();
  }

#pragma unroll
  for (int i = 0; i < 4; ++i) {
#pragma unroll
    for (int j = 0; j < 4; ++j) {
#pragma unroll
      for (int r = 0; r < 4; ++r) {
        const int gr = m0 + wm + i * 16 + q4 * 4 + r;
        const int gc = n0 + wn + j * 16 + lm;
        const size_t idx = (size_t)gr * DM + gc;
        const float vq = accq[i][j][r] * QSCALE;
        const __bf16 qhv = (__bf16)vq;
        Qh[idx] = qhv;
        Ql[idx] = (__bf16)(vq - (float)qhv);
        const float vk = acck[i][j][r];
        const __bf16 khv = (__bf16)vk;
        Kh[idx] = khv;
        Kl[idx] = (__bf16)(vk - (float)khv);
      }
    }
  }
}

// ---------------- flash attention (mi=4: 64 q-rows/wave, prefetch pipeline) --
// grid: 512 logical tiles (bh*8 + qtile), XCD-swizzled; block = 256 (4 waves,
// each wave owns 64 q rows -> 256 q-rows per block). Same 16 K-reads feed 96
// score MFMAs and 8 V-reads feed 32 PV MFMAs per wave-iter. Transposed scores,
// P in-register via tau-permuted V. K/V double-buffered (49152 B), R3
// single-barrier prefetch pipeline. VGPR 128, no spill under (256,2).
__global__ void __launch_bounds__(256, 2) flash_kernel(const __bf16* __restrict__ Qh,
                                                       const __bf16* __restrict__ Ql,
                                                       const __bf16* __restrict__ Kh,
                                                       const __bf16* __restrict__ Kl,
                                                       const __bf16* __restrict__ Vt,
                                                       __bf16* __restrict__ Mg) {
  __shared__ __align__(16) __bf16 sKh[2][64 * 64];
  __shared__ __align__(16) __bf16 sKl[2][64 * 64];
  __shared__ __align__(16) __bf16 sV[2][64 * 64];

  const int tid = threadIdx.x;
  const int lid = xcd_swz512(blockIdx.x);
  const int qt = lid & 7;              // 8 q-tiles of 256
  const int bh = lid >> 3;             // 64 (b,h) pairs
  const int b = bh >> 4;
  const int h = bh & 15;
  const int mq0 = b * SEQ + qt * 256;
  const int ch = h * 64;
  const int w = tid >> 6;
  const int lane = tid & 63;
  const int lm = lane & 15;
  const int q4 = lane >> 4;

  // staging geometry: two 16B chunks per thread, swizzle chunk ^ (row&7)
  const int c0 = tid, c1 = tid + 256;
  const int r0 = c0 >> 3, e0 = ((c0 & 7) ^ (r0 & 7)) << 3;
  const int r1 = c1 >> 3, e1 = ((c1 & 7) ^ (r1 & 7)) << 3;

  // prologue: stage Q (256 rows) in 4 passes of 64 through K buf0 -> regs.
  // wave w owns q rows [w*64, w*64+64): all of pass p == w.
  bf16x8 qh[4][2], ql[4][2];  // [mi][ks]
#pragma unroll
  for (int p = 0; p < 4; ++p) {
    const size_t gq0 = (size_t)(mq0 + p * 64 + r0) * DM + ch + e0;
    const size_t gq1 = (size_t)(mq0 + p * 64 + r1) * DM + ch + e1;
    async16(Qh + gq0, &sKh[0][c0 * 8]);
    async16(Ql + gq0, &sKl[0][c0 * 8]);
    async16(Qh + gq1, &sKh[0][c1 * 8]);
    async16(Ql + gq1, &sKl[0][c1 * 8]);
    __syncthreads();
    if (w == p) {
#pragma unroll
      for (int mi = 0; mi < 4; ++mi) {
        const int rq = mi * 16 + lm;  // row within this 64-row pass
#pragma unroll
        for (int ks = 0; ks < 2; ++ks) {
          const int oq = rq * 64 + (((ks * 4 + q4) ^ (rq & 7)) << 3);
          qh[mi][ks] = *(const bf16x8*)&sKh[0][oq];
          ql[mi][ks] = *(const bf16x8*)&sKl[0][oq];
        }
      }
    }
    __syncthreads();
  }

  // hoisted K/V fragment LDS offsets (same formula both)
  int ofr[2][4];
#pragma unroll
  for (int ks = 0; ks < 2; ++ks)
#pragma unroll
    for (int t = 0; t < 4; ++t) {
      const int rk = t * 16 + lm;
      ofr[ks][t] = rk * 64 + (((ks * 4 + q4) ^ (rk & 7)) << 3);
    }

  // per-lane softmax state: one q-column per mi tile (q = mi*16 + lm)
  floatx4 o[4][4];                      // [mi][dt], O^T layout: col=q(lm), row=d
  const floatx4 fz = {0.f, 0.f, 0.f, 0.f};
#pragma unroll
  for (int mi = 0; mi < 4; ++mi)
#pragma unroll
    for (int dt = 0; dt < 4; ++dt) o[mi][dt] = fz;
  float lsum[4] = {0.f, 0.f, 0.f, 0.f};
  float m[4] = {-1e30f, -1e30f, -1e30f, -1e30f};

  // rolling staging offsets
  size_t gk0 = (size_t)(b * SEQ + r0) * DM + ch + e0;
  size_t gk1 = (size_t)(b * SEQ + r1) * DM + ch + e1;
  size_t gv0 = (size_t)(bh * 64 + r0) * SEQ + e0;
  size_t gv1 = (size_t)(bh * 64 + r1) * SEQ + e1;

  // prologue stage: tile 0 -> buf0 (6 loads in flight)
  async16(Kh + gk0, &sKh[0][c0 * 8]);
  async16(Kl + gk0, &sKl[0][c0 * 8]);
  async16(Kh + gk1, &sKh[0][c1 * 8]);
  async16(Kl + gk1, &sKl[0][c1 * 8]);
  async16(Vt + gv0, &sV[0][c0 * 8]);
  async16(Vt + gv1, &sV[0][c1 * 8]);
  gk0 += (size_t)64 * DM;
  gk1 += (size_t)64 * DM;
  gv0 += 64;
  gv1 += 64;

  for (int it = 0; it < 32; ++it) {
    const int cur = it & 1;
    // loads for buf[cur] were issued one compute-phase ago; wait + sync
    asm volatile("s_waitcnt vmcnt(0)" ::: "memory");
    __builtin_amdgcn_s_barrier();
    __builtin_amdgcn_sched_barrier(0);
    // issue next-tile loads into the other buffer (overlaps this compute)
    if (it < 31) {
      const int nxt = cur ^ 1;
      async16(Kh + gk0, &sKh[nxt][c0 * 8]);
      async16(Kl + gk0, &sKl[nxt][c0 * 8]);
      async16(Kh + gk1, &sKh[nxt][c1 * 8]);
      async16(Kl + gk1, &sKl[nxt][c1 * 8]);
      async16(Vt + gv0, &sV[nxt][c0 * 8]);
      async16(Vt + gv1, &sV[nxt][c1 * 8]);
      gk0 += (size_t)64 * DM;
      gk1 += (size_t)64 * DM;
      gv0 += 64;
      gv1 += 64;
    }
    const __bf16* bKh = sKh[cur];
    const __bf16* bKl = sKl[cur];
    const __bf16* bV = sV[cur];

    // scores TRANSPOSED: s2[nt][mi] = S^T tile [key 16 x q 16], 3-term, log2 domain
    floatx4 s2[4][4];
#pragma unroll
    for (int nt = 0; nt < 4; ++nt)
#pragma unroll
      for (int mi = 0; mi < 4; ++mi) s2[nt][mi] = fz;
#pragma unroll
    for (int ks = 0; ks < 2; ++ks) {
#pragma unroll
      for (int nt = 0; nt < 4; ++nt) {
        const bf16x8 kh = *(const bf16x8*)&bKh[ofr[ks][nt]];
        const bf16x8 kl = *(const bf16x8*)&bKl[ofr[ks][nt]];
#pragma unroll
        for (int mi = 0; mi < 4; ++mi) {
          s2[nt][mi] = mfma16(kh, qh[mi][ks], s2[nt][mi]);
          s2[nt][mi] = mfma16(kl, qh[mi][ks], s2[nt][mi]);
          s2[nt][mi] = mfma16(kh, ql[mi][ks], s2[nt][mi]);
        }
      }
    }

    // per-lane tile max over this lane's 16 keys, then reduce across q4 lanes
    float tm[4];
    bool need = false;
#pragma unroll
    for (int mi = 0; mi < 4; ++mi) {
      float mx = fmaxf(fmaxf(s2[0][mi][0], s2[0][mi][1]),
                       fmaxf(s2[0][mi][2], s2[0][mi][3]));
#pragma unroll
      for (int nt = 1; nt < 4; ++nt) {
        mx = fmaxf(mx, fmaxf(fmaxf(s2[nt][mi][0], s2[nt][mi][1]),
                             fmaxf(s2[nt][mi][2], s2[nt][mi][3])));
      }
      mx = fmaxf(mx, __shfl_xor(mx, 16));
      mx = fmaxf(mx, __shfl_xor(mx, 32));
      tm[mi] = mx;
      need = need || (mx > m[mi] + 8.f);
    }
    // defer-max: only rescale when a tile max exceeds running max by >8 (P<=2^8)
    if (__ballot(need)) {
#pragma unroll
      for (int mi = 0; mi < 4; ++mi) {
        const float mn = fmaxf(m[mi], tm[mi]);
        const float a = __builtin_amdgcn_exp2f(m[mi] - mn);
        m[mi] = mn;
        lsum[mi] *= a;
#pragma unroll
        for (int dt = 0; dt < 4; ++dt) o[mi][dt] *= a;
      }
    }

    // P = exp2(s - m) packed DIRECTLY into the PV B-fragment (lane-local thanks
    // to the tau-permuted V key order): aP[mi][ks][(nt&1)*4+r] = p[nt][r], ks=nt>>1.
    // Row-sum accumulated in fp32 registers.
    bf16x8 aP[4][2];
#pragma unroll
    for (int mi = 0; mi < 4; ++mi) {
      float ps = 0.f;
#pragma unroll
      for (int nt = 0; nt < 4; ++nt) {
#pragma unroll
        for (int r = 0; r < 4; ++r) {
          const float p = __builtin_amdgcn_exp2f(s2[nt][mi][r] - m[mi]);
          ps += p;
          aP[mi][nt >> 1][(nt & 1) * 4 + r] = (__bf16)p;
        }
      }
      ps += __shfl_xor(ps, 16);
      ps += __shfl_xor(ps, 32);
      lsum[mi] += ps;
    }

    // PV transposed: O^T[d][q] += V^T[d,k] * P[q,k]  (A=V^T frag, B=aP in regs)
#pragma unroll
    for (int ks = 0; ks < 2; ++ks) {
#pragma unroll
      for (int dt = 0; dt < 4; ++dt) {
        const bf16x8 bv = *(const bf16x8*)&bV[ofr[ks][dt]];
#pragma unroll
        for (int mi = 0; mi < 4; ++mi)
          o[mi][dt] = mfma16(bv, aP[mi][ks], o[mi][dt]);
      }
    }
    // no second barrier: next iteration's barrier guarantees all waves finished
    // reading buf[cur] before any wave issues loads into it
  }

  // epilogue: normalize and store merged [B*S, D] bf16; O^T layout means each
  // lane owns q = w*64 + mi*16 + lm and 4 consecutive d per dt -> packed 8B
#pragma unroll
  for (int mi = 0; mi < 4; ++mi) {
    const float inv = __builtin_amdgcn_rcpf(lsum[mi]);
    const int gr = mq0 + w * 64 + mi * 16 + lm;
#pragma unroll
    for (int dt = 0; dt < 4; ++dt) {
      bf16x4 ov;
#pragma unroll
      for (int r = 0; r < 4; ++r) ov[r] = (__bf16)(o[mi][dt][r] * inv);
      *(bf16x4*)&Mg[(size_t)gr * DM + ch + dt * 16 + q4 * 4] = ov;
    }
  }
}

// ---------------- launch ----------------

extern "C" void kernel_launch(void* const* d_in, const int* in_sizes, int n_in,
                              void* d_out, int out_size, void* d_ws, size_t ws_size,
                              hipStream_t stream) {
  (void)in_sizes; (void)n_in; (void)out_size; (void)ws_size;
  const float* x  = (const float*)d_in[0];
  const float* Wq = (const float*)d_in[1];
  const float* Wk = (const float*)d_in[2];
  const float* Wv = (const float*)d_in[3];
  const float* fc = (const float*)d_in[4];
  float* out = (float*)d_out;

  char* base = (char*)d_ws;
  const size_t XB = (size_t)MROWS * DM * 2;  // 16 MiB
  const size_t WB = (size_t)DM * DM * 2;     // 2 MiB
  __bf16* xh  = (__bf16*)(base);
  __bf16* xl  = (__bf16*)(base + XB);
  __bf16* wqh = (__bf16*)(base + 2 * XB);
  __bf16* wql = (__bf16*)(base + 2 * XB + WB);
  __bf16* wkh = (__bf16*)(base + 2 * XB + 2 * WB);
  __bf16* wkl = (__bf16*)(base + 2 * XB + 3 * WB);
  __bf16* wvh = (__bf16*)(base + 2 * XB + 4 * WB);
  __bf16* fch = (__bf16*)(base + 2 * XB + 5 * WB);
  __bf16* Qh  = (__bf16*)(base + 2 * XB + 6 * WB);
  __bf16* Ql  = (__bf16*)(base + 3 * XB + 6 * WB);
  __bf16* Kh  = (__bf16*)(base + 4 * XB + 6 * WB);
  __bf16* Kl  = (__bf16*)(base + 5 * XB + 6 * WB);
  __bf16* Vt  = xl;  // xl dead after QK projection
  __bf16* Mg  = xh;  // xh dead after V projection

  split_x_kernel<<<dim3(8192), dim3(256), 0, stream>>>(x, xh, xl);
  wtrans4_kernel<<<dim3(4096), dim3(256), 0, stream>>>(Wq, Wk, Wv, fc,
                                                       wqh, wql, wkh, wkl, wvh, fch);

  // fused Q+K projection (Q pre-scaled by 0.125*log2(e) for base-2 flash softmax)
  gemm_qk<<<dim3(512), dim3(256), 0, stream>>>(xh, xl, wqh, wql, wkh, wkl, Qh, Ql, Kh, Kl);
  gemm_nt<3><<<dim3(512), dim3(256), 0, stream>>>(xh, wvh, (void*)Vt);

  flash_kernel<<<dim3(512), dim3(256), 0, stream>>>(Qh, Ql, Kh, Kl, Vt, Mg);

  gemm_nt<1><<<dim3(512), dim3(256), 0, stream>>>(Mg, fch, (void*)out);
}

// Round 12
// 372.067 us; speedup vs baseline: 1.0462x; 1.0462x over previous
//
#include <hip/hip_runtime.h>
#include <stdint.h>

#define MROWS 8192   // B*S
#define DM    1024
#define NH    16
#define HD    64
#define SEQ   2048

typedef __bf16 bf16x8 __attribute__((ext_vector_type(8)));
typedef __bf16 bf16x4 __attribute__((ext_vector_type(4)));
typedef float  floatx4 __attribute__((ext_vector_type(4)));

// 0.125 (1/sqrt(64)) * log2(e): folded into Q so flash scores are already base-2
#define QSCALE 0.18033688011112042f

// T1 XCD-aware swizzle for 512-block grids (512 % 8 == 0 -> bijective):
// hardware slot bid runs logical tile (bid%8)*64 + bid/8, so each XCD gets 64
// CONSECUTIVE logical tiles -> blocks sharing an A-panel / K,V head sit on the
// same XCD's L2 instead of being round-robined across all 8.
__device__ __forceinline__ int xcd_swz512(int bid) {
  return ((bid & 7) << 6) | (bid >> 3);
}

__device__ __forceinline__ void async16(const void* g, void* l) {
  __builtin_amdgcn_global_load_lds(
      (__attribute__((address_space(1))) void*)g,
      (__attribute__((address_space(3))) void*)l,
      16, 0, 0);
}

__device__ __forceinline__ floatx4 mfma16(bf16x8 a, bf16x8 b, floatx4 c) {
  return __builtin_amdgcn_mfma_f32_16x16x32_bf16(a, b, c, 0, 0, 0);
}

// ---------------- conversion kernels ----------------

__global__ void __launch_bounds__(256) split_x_kernel(const float* __restrict__ x,
                                                      __bf16* __restrict__ xh,
                                                      __bf16* __restrict__ xl) {
  const int i = blockIdx.x * 256 + threadIdx.x;
  const float4 v = reinterpret_cast<const float4*>(x)[i];
  const float vv[4] = {v.x, v.y, v.z, v.w};
  bf16x4 H, L;
#pragma unroll
  for (int j = 0; j < 4; ++j) {
    const __bf16 h = (__bf16)vv[j];
    H[j] = h;
    L[j] = (__bf16)(vv[j] - (float)h);
  }
  reinterpret_cast<bf16x4*>(xh)[i] = H;
  reinterpret_cast<bf16x4*>(xl)[i] = L;
}

// All 4 weight transposes in one launch: W [K][N] fp32 -> W^T [N][K] bf16
// hi (+ lo for Wq/Wk). which = blockIdx.x>>10 selects the matrix.
__global__ void __launch_bounds__(256) wtrans4_kernel(
    const float* __restrict__ Wq, const float* __restrict__ Wk,
    const float* __restrict__ Wv, const float* __restrict__ Wf,
    __bf16* __restrict__ Tqh, __bf16* __restrict__ Tql,
    __bf16* __restrict__ Tkh, __bf16* __restrict__ Tkl,
    __bf16* __restrict__ Tvh, __bf16* __restrict__ Tfh) {
  const int which = blockIdx.x >> 10;
  const int blk = blockIdx.x & 1023;
  const float* W = (which == 0) ? Wq : (which == 1) ? Wk : (which == 2) ? Wv : Wf;
  __bf16* Th = (which == 0) ? Tqh : (which == 1) ? Tkh : (which == 2) ? Tvh : Tfh;
  __bf16* Tl = (which == 0) ? Tql : (which == 1) ? Tkl : (__bf16*)nullptr;

  __shared__ float t[32][33];
  const int tx = threadIdx.x & 31, ty = threadIdx.x >> 5;
  const int bx = blk & 31, by = blk >> 5;
#pragma unroll
  for (int j = 0; j < 4; ++j) {
    const int k = by * 32 + ty + j * 8;
    t[ty + j * 8][tx] = W[(size_t)k * DM + bx * 32 + tx];
  }
  __syncthreads();
#pragma unroll
  for (int j = 0; j < 4; ++j) {
    const int n = bx * 32 + ty + j * 8;
    const int k = by * 32 + tx;
    const float v = t[tx][ty + j * 8];
    const __bf16 h = (__bf16)v;
    Th[(size_t)n * DM + k] = h;
    if (Tl) Tl[(size_t)n * DM + k] = (__bf16)(v - (float)h);
  }
}

// ---------------- NT GEMM (1-term): C[M,N] = A[M,K] * B^T ----------------
// OUTMODE: 1 = fp32, 3 = bf16 transposed per-head with PERMUTED key order:
//   Vt[b,h,d, 64*(s/64) + tauinv(s%64)]
// tauinv(a) = (a&32) | ((a&12)<<1) | ((a&16)>>2) | (a&3).
// This makes the flash PV B-fragment lane-local: V LDS position p = 32ks+8q4+e
// holds actual key tau(p) = 16*(2ks+(e>>2)) + 4q4 + (e&3), exactly the key that
// lane (lm,q4) holds in its score register s2[2ks+(e>>2)][.][e&3].
// (R11's dbuf experiment was neutral-to-negative at 2 blocks/CU -> reverted to
// the 2-phase structure; inter-wave overlap already hides the drain here.)
template <int OUTMODE>
__global__ void __launch_bounds__(256) gemm_nt(const __bf16* __restrict__ Ah,
                                               const __bf16* __restrict__ Bh,
                                               void* __restrict__ C0) {
  __shared__ __align__(16) __bf16 sAh[128 * 32];
  __shared__ __align__(16) __bf16 sBh[128 * 32];

  const int tid = threadIdx.x;
  const int lid = xcd_swz512(blockIdx.x);
  const int bm = lid >> 3;
  const int bn = lid & 7;
  const int m0 = bm << 7, n0 = bn << 7;
  const int w = tid >> 6;
  const int lane = tid & 63;
  const int wm = (w >> 1) << 6;
  const int wn = (w & 1) << 6;
  const int lm = lane & 15;
  const int q4 = lane >> 4;

  floatx4 acc[4][4];
  const floatx4 fz = {0.f, 0.f, 0.f, 0.f};
#pragma unroll
  for (int i = 0; i < 4; ++i)
#pragma unroll
    for (int j = 0; j < 4; ++j) acc[i][j] = fz;

  const int c0 = tid, c1 = tid + 256;
  const int row0 = c0 >> 2, cc0 = (c0 & 3) ^ ((row0 >> 1) & 3);
  const int row1 = c1 >> 2, cc1 = (c1 & 3) ^ ((row1 >> 1) & 3);

  int offA[4], offB[4];
#pragma unroll
  for (int i = 0; i < 4; ++i) {
    const int ra = wm + i * 16 + lm;
    offA[i] = ra * 32 + ((q4 ^ ((ra >> 1) & 3)) << 3);
    const int rb = wn + i * 16 + lm;
    offB[i] = rb * 32 + ((q4 ^ ((rb >> 1) & 3)) << 3);
  }

  size_t ga0 = (size_t)(m0 + row0) * DM + cc0 * 8;
  size_t gb0 = (size_t)(n0 + row0) * DM + cc0 * 8;
  size_t ga1 = (size_t)(m0 + row1) * DM + cc1 * 8;
  size_t gb1 = (size_t)(n0 + row1) * DM + cc1 * 8;

  for (int it = 0; it < 32; ++it) {
    async16(Ah + ga0, &sAh[c0 * 8]);
    async16(Bh + gb0, &sBh[c0 * 8]);
    async16(Ah + ga1, &sAh[c1 * 8]);
    async16(Bh + gb1, &sBh[c1 * 8]);
    ga0 += 32; gb0 += 32; ga1 += 32; gb1 += 32;
    __syncthreads();

    bf16x8 ah[4], bh[4];
#pragma unroll
    for (int i = 0; i < 4; ++i) {
      ah[i] = *(const bf16x8*)&sAh[offA[i]];
      bh[i] = *(const bf16x8*)&sBh[offB[i]];
    }
#pragma unroll
    for (int i = 0; i < 4; ++i)
#pragma unroll
      for (int j = 0; j < 4; ++j)
        acc[i][j] = mfma16(ah[i], bh[j], acc[i][j]);
    __syncthreads();
  }

#pragma unroll
  for (int i = 0; i < 4; ++i) {
#pragma unroll
    for (int j = 0; j < 4; ++j) {
#pragma unroll
      for (int r = 0; r < 4; ++r) {
        const int gr = m0 + wm + i * 16 + q4 * 4 + r;
        const int gc = n0 + wn + j * 16 + lm;
        const float v = acc[i][j][r];
        if constexpr (OUTMODE == 1) {
          ((float*)C0)[(size_t)gr * DM + gc] = v;
        } else {
          const int bb = gr >> 11, ss = gr & 2047;
          const int s6 = ss & 63;
          const int sp = (ss & ~63) | (s6 & 32) | ((s6 & 12) << 1) |
                         ((s6 & 16) >> 2) | (s6 & 3);
          const int hh = gc >> 6, dd = gc & 63;
          ((__bf16*)C0)[(((size_t)(bb * NH + hh) << 6) + dd) * SEQ + sp] = (__bf16)v;
        }
      }
    }
  }
}

// ---------------- fused Q+K projection GEMM ----------------
// C_q = A*Bq^T (scaled by QSCALE, hi/lo split), C_k = A*Bk^T (hi/lo split).
// Shares A staging and A fragments across both outputs. 3-term hi/lo product.
__global__ void __launch_bounds__(256, 2) gemm_qk(const __bf16* __restrict__ Ah,
                                                  const __bf16* __restrict__ Al,
                                                  const __bf16* __restrict__ Bqh,
                                                  const __bf16* __restrict__ Bql,
                                                  const __bf16* __restrict__ Bkh,
                                                  const __bf16* __restrict__ Bkl,
                                                  __bf16* __restrict__ Qh,
                                                  __bf16* __restrict__ Ql,
                                                  __bf16* __restrict__ Kh,
                                                  __bf16* __restrict__ Kl) {
  __shared__ __align__(16) __bf16 sAh[128 * 32];
  __shared__ __align__(16) __bf16 sAl[128 * 32];
  __shared__ __align__(16) __bf16 sQh_[128 * 32];
  __shared__ __align__(16) __bf16 sQl_[128 * 32];
  __shared__ __align__(16) __bf16 sKh_[128 * 32];
  __shared__ __align__(16) __bf16 sKl_[128 * 32];

  const int tid = threadIdx.x;
  const int lid = xcd_swz512(blockIdx.x);
  const int bm = lid >> 3;
  const int bn = lid & 7;
  const int m0 = bm << 7, n0 = bn << 7;
  const int w = tid >> 6;
  const int lane = tid & 63;
  const int wm = (w >> 1) << 6;
  const int wn = (w & 1) << 6;
  const int lm = lane & 15;
  const int q4 = lane >> 4;

  floatx4 accq[4][4], acck[4][4];
  const floatx4 fz = {0.f, 0.f, 0.f, 0.f};
#pragma unroll
  for (int i = 0; i < 4; ++i)
#pragma unroll
    for (int j = 0; j < 4; ++j) { accq[i][j] = fz; acck[i][j] = fz; }

  const int c0 = tid, c1 = tid + 256;
  const int row0 = c0 >> 2, cc0 = (c0 & 3) ^ ((row0 >> 1) & 3);
  const int row1 = c1 >> 2, cc1 = (c1 & 3) ^ ((row1 >> 1) & 3);

  int offA[4], offB[4];
#pragma unroll
  for (int i = 0; i < 4; ++i) {
    const int ra = wm + i * 16 + lm;
    offA[i] = ra * 32 + ((q4 ^ ((ra >> 1) & 3)) << 3);
    const int rb = wn + i * 16 + lm;
    offB[i] = rb * 32 + ((q4 ^ ((rb >> 1) & 3)) << 3);
  }

  size_t ga0 = (size_t)(m0 + row0) * DM + cc0 * 8;
  size_t gb0 = (size_t)(n0 + row0) * DM + cc0 * 8;
  size_t ga1 = (size_t)(m0 + row1) * DM + cc1 * 8;
  size_t gb1 = (size_t)(n0 + row1) * DM + cc1 * 8;

  for (int it = 0; it < 32; ++it) {
    async16(Ah + ga0, &sAh[c0 * 8]);
    async16(Al + ga0, &sAl[c0 * 8]);
    async16(Ah + ga1, &sAh[c1 * 8]);
    async16(Al + ga1, &sAl[c1 * 8]);
    async16(Bqh + gb0, &sQh_[c0 * 8]);
    async16(Bql + gb0, &sQl_[c0 * 8]);
    async16(Bqh + gb1, &sQh_[c1 * 8]);
    async16(Bql + gb1, &sQl_[c1 * 8]);
    async16(Bkh + gb0, &sKh_[c0 * 8]);
    async16(Bkl + gb0, &sKl_[c0 * 8]);
    async16(Bkh + gb1, &sKh_[c1 * 8]);
    async16(Bkl + gb1, &sKl_[c1 * 8]);
    ga0 += 32; gb0 += 32; ga1 += 32; gb1 += 32;
    __syncthreads();

    bf16x8 ah[4], al[4];
#pragma unroll
    for (int i = 0; i < 4; ++i) {
      ah[i] = *(const bf16x8*)&sAh[offA[i]];
      al[i] = *(const bf16x8*)&sAl[offA[i]];
    }
    // Q phase
    {
      bf16x8 bh[4], bl[4];
#pragma unroll
      for (int j = 0; j < 4; ++j) {
        bh[j] = *(const bf16x8*)&sQh_[offB[j]];
        bl[j] = *(const bf16x8*)&sQl_[offB[j]];
      }
#pragma unroll
      for (int i = 0; i < 4; ++i)
#pragma unroll
        for (int j = 0; j < 4; ++j) {
          accq[i][j] = mfma16(ah[i], bh[j], accq[i][j]);
          accq[i][j] = mfma16(ah[i], bl[j], accq[i][j]);
          accq[i][j] = mfma16(al[i], bh[j], accq[i][j]);
        }
    }
    // K phase
    {
      bf16x8 bh[4], bl[4];
#pragma unroll
      for (int j = 0; j < 4; ++j) {
        bh[j] = *(const bf16x8*)&sKh_[offB[j]];
        bl[j] = *(const bf16x8*)&sKl_[offB[j]];
      }
#pragma unroll
      for (int i = 0; i < 4; ++i)
#pragma unroll
        for (int j = 0; j < 4; ++j) {
          acck[i][j] = mfma16(ah[i], bh[j], acck[i][j]);
          acck[i][j] = mfma16(ah[i], bl[j], acck[i][j]);
          acck[i][j] = mfma16(al[i], bh[j], acck[i][j]);
        }
    }
    __syncthreads();
  }

#pragma unroll
  for (int i = 0; i < 4; ++i) {
#pragma unroll
    for (int j = 0; j < 4; ++j) {
#pragma unroll
      for (int r = 0; r < 4; ++r) {
        const int gr = m0 + wm + i * 16 + q4 * 4 + r;
        const int gc = n0 + wn + j * 16 + lm;
        const size_t idx = (size_t)gr * DM + gc;
        const float vq = accq[i][j][r] * QSCALE;
        const __bf16 qhv = (__bf16)vq;
        Qh[idx] = qhv;
        Ql[idx] = (__bf16)(vq - (float)qhv);
        const float vk = acck[i][j][r];
        const __bf16 khv = (__bf16)vk;
        Kh[idx] = khv;
        Kl[idx] = (__bf16)(vk - (float)khv);
      }
    }
  }
}

// ---------------- flash attention (mi=4: 64 q-rows/wave, prefetch pipeline) --
// grid: 512 logical tiles (bh*8 + qtile), XCD-swizzled; block = 256 (4 waves,
// each wave owns 64 q rows -> 256 q-rows per block). Same 16 K-reads feed 96
// score MFMAs and 8 V-reads feed 32 PV MFMAs per wave-iter. Transposed scores,
// P in-register via tau-permuted V. K/V double-buffered (49152 B), R3
// single-barrier prefetch pipeline. VGPR 128, no spill under (256,2).
// R12: Q prologue loads straight global->register (for fixed (mi,ks) the 4 q4
// lanes cover one full 64B sector per row -> perfect coalescing), removing the
// 4-pass LDS staging and its 8 __syncthreads.
__global__ void __launch_bounds__(256, 2) flash_kernel(const __bf16* __restrict__ Qh,
                                                       const __bf16* __restrict__ Ql,
                                                       const __bf16* __restrict__ Kh,
                                                       const __bf16* __restrict__ Kl,
                                                       const __bf16* __restrict__ Vt,
                                                       __bf16* __restrict__ Mg) {
  __shared__ __align__(16) __bf16 sKh[2][64 * 64];
  __shared__ __align__(16) __bf16 sKl[2][64 * 64];
  __shared__ __align__(16) __bf16 sV[2][64 * 64];

  const int tid = threadIdx.x;
  const int lid = xcd_swz512(blockIdx.x);
  const int qt = lid & 7;              // 8 q-tiles of 256
  const int bh = lid >> 3;             // 64 (b,h) pairs
  const int b = bh >> 4;
  const int h = bh & 15;
  const int mq0 = b * SEQ + qt * 256;
  const int ch = h * 64;
  const int w = tid >> 6;
  const int lane = tid & 63;
  const int lm = lane & 15;
  const int q4 = lane >> 4;

  // staging geometry: two 16B chunks per thread, swizzle chunk ^ (row&7)
  const int c0 = tid, c1 = tid + 256;
  const int r0 = c0 >> 3, e0 = ((c0 & 7) ^ (r0 & 7)) << 3;
  const int r1 = c1 >> 3, e1 = ((c1 & 7) ^ (r1 & 7)) << 3;

  // rolling staging offsets
  size_t gk0 = (size_t)(b * SEQ + r0) * DM + ch + e0;
  size_t gk1 = (size_t)(b * SEQ + r1) * DM + ch + e1;
  size_t gv0 = (size_t)(bh * 64 + r0) * SEQ + e0;
  size_t gv1 = (size_t)(bh * 64 + r1) * SEQ + e1;

  // prologue stage: K/V tile 0 -> buf0 (6 loads in flight, issued FIRST so
  // they overlap the Q register loads below)
  async16(Kh + gk0, &sKh[0][c0 * 8]);
  async16(Kl + gk0, &sKl[0][c0 * 8]);
  async16(Kh + gk1, &sKh[0][c1 * 8]);
  async16(Kl + gk1, &sKl[0][c1 * 8]);
  async16(Vt + gv0, &sV[0][c0 * 8]);
  async16(Vt + gv1, &sV[0][c1 * 8]);
  gk0 += (size_t)64 * DM;
  gk1 += (size_t)64 * DM;
  gv0 += 64;
  gv1 += 64;

  // Q prologue: direct global -> register (no LDS, no barriers)
  bf16x8 qh[4][2], ql[4][2];  // [mi][ks]
#pragma unroll
  for (int mi = 0; mi < 4; ++mi) {
    const size_t qrow = (size_t)(mq0 + w * 64 + mi * 16 + lm) * DM + ch;
#pragma unroll
    for (int ks = 0; ks < 2; ++ks) {
      qh[mi][ks] = *(const bf16x8*)&Qh[qrow + ks * 32 + q4 * 8];
      ql[mi][ks] = *(const bf16x8*)&Ql[qrow + ks * 32 + q4 * 8];
    }
  }

  // hoisted K/V fragment LDS offsets (same formula both)
  int ofr[2][4];
#pragma unroll
  for (int ks = 0; ks < 2; ++ks)
#pragma unroll
    for (int t = 0; t < 4; ++t) {
      const int rk = t * 16 + lm;
      ofr[ks][t] = rk * 64 + (((ks * 4 + q4) ^ (rk & 7)) << 3);
    }

  // per-lane softmax state: one q-column per mi tile (q = mi*16 + lm)
  floatx4 o[4][4];                      // [mi][dt], O^T layout: col=q(lm), row=d
  const floatx4 fz = {0.f, 0.f, 0.f, 0.f};
#pragma unroll
  for (int mi = 0; mi < 4; ++mi)
#pragma unroll
    for (int dt = 0; dt < 4; ++dt) o[mi][dt] = fz;
  float lsum[4] = {0.f, 0.f, 0.f, 0.f};
  float m[4] = {-1e30f, -1e30f, -1e30f, -1e30f};

  for (int it = 0; it < 32; ++it) {
    const int cur = it & 1;
    // loads for buf[cur] were issued one compute-phase ago; wait + sync
    asm volatile("s_waitcnt vmcnt(0)" ::: "memory");
    __builtin_amdgcn_s_barrier();
    __builtin_amdgcn_sched_barrier(0);
    // issue next-tile loads into the other buffer (overlaps this compute)
    if (it < 31) {
      const int nxt = cur ^ 1;
      async16(Kh + gk0, &sKh[nxt][c0 * 8]);
      async16(Kl + gk0, &sKl[nxt][c0 * 8]);
      async16(Kh + gk1, &sKh[nxt][c1 * 8]);
      async16(Kl + gk1, &sKl[nxt][c1 * 8]);
      async16(Vt + gv0, &sV[nxt][c0 * 8]);
      async16(Vt + gv1, &sV[nxt][c1 * 8]);
      gk0 += (size_t)64 * DM;
      gk1 += (size_t)64 * DM;
      gv0 += 64;
      gv1 += 64;
    }
    const __bf16* bKh = sKh[cur];
    const __bf16* bKl = sKl[cur];
    const __bf16* bV = sV[cur];

    // scores TRANSPOSED: s2[nt][mi] = S^T tile [key 16 x q 16], 3-term, log2 domain
    floatx4 s2[4][4];
#pragma unroll
    for (int nt = 0; nt < 4; ++nt)
#pragma unroll
      for (int mi = 0; mi < 4; ++mi) s2[nt][mi] = fz;
#pragma unroll
    for (int ks = 0; ks < 2; ++ks) {
#pragma unroll
      for (int nt = 0; nt < 4; ++nt) {
        const bf16x8 kh = *(const bf16x8*)&bKh[ofr[ks][nt]];
        const bf16x8 kl = *(const bf16x8*)&bKl[ofr[ks][nt]];
#pragma unroll
        for (int mi = 0; mi < 4; ++mi) {
          s2[nt][mi] = mfma16(kh, qh[mi][ks], s2[nt][mi]);
          s2[nt][mi] = mfma16(kl, qh[mi][ks], s2[nt][mi]);
          s2[nt][mi] = mfma16(kh, ql[mi][ks], s2[nt][mi]);
        }
      }
    }

    // per-lane tile max over this lane's 16 keys, then reduce across q4 lanes
    float tm[4];
    bool need = false;
#pragma unroll
    for (int mi = 0; mi < 4; ++mi) {
      float mx = fmaxf(fmaxf(s2[0][mi][0], s2[0][mi][1]),
                       fmaxf(s2[0][mi][2], s2[0][mi][3]));
#pragma unroll
      for (int nt = 1; nt < 4; ++nt) {
        mx = fmaxf(mx, fmaxf(fmaxf(s2[nt][mi][0], s2[nt][mi][1]),
                             fmaxf(s2[nt][mi][2], s2[nt][mi][3])));
      }
      mx = fmaxf(mx, __shfl_xor(mx, 16));
      mx = fmaxf(mx, __shfl_xor(mx, 32));
      tm[mi] = mx;
      need = need || (mx > m[mi] + 8.f);
    }
    // defer-max: only rescale when a tile max exceeds running max by >8 (P<=2^8)
    if (__ballot(need)) {
#pragma unroll
      for (int mi = 0; mi < 4; ++mi) {
        const float mn = fmaxf(m[mi], tm[mi]);
        const float a = __builtin_amdgcn_exp2f(m[mi] - mn);
        m[mi] = mn;
        lsum[mi] *= a;
#pragma unroll
        for (int dt = 0; dt < 4; ++dt) o[mi][dt] *= a;
      }
    }

    // P = exp2(s - m) packed DIRECTLY into the PV B-fragment (lane-local thanks
    // to the tau-permuted V key order): aP[mi][ks][(nt&1)*4+r] = p[nt][r], ks=nt>>1.
    // Row-sum accumulated in fp32 registers.
    bf16x8 aP[4][2];
#pragma unroll
    for (int mi = 0; mi < 4; ++mi) {
      float ps = 0.f;
#pragma unroll
      for (int nt = 0; nt < 4; ++nt) {
#pragma unroll
        for (int r = 0; r < 4; ++r) {
          const float p = __builtin_amdgcn_exp2f(s2[nt][mi][r] - m[mi]);
          ps += p;
          aP[mi][nt >> 1][(nt & 1) * 4 + r] = (__bf16)p;
        }
      }
      ps += __shfl_xor(ps, 16);
      ps += __shfl_xor(ps, 32);
      lsum[mi] += ps;
    }

    // PV transposed: O^T[d][q] += V^T[d,k] * P[q,k]  (A=V^T frag, B=aP in regs)
#pragma unroll
    for (int ks = 0; ks < 2; ++ks) {
#pragma unroll
      for (int dt = 0; dt < 4; ++dt) {
        const bf16x8 bv = *(const bf16x8*)&bV[ofr[ks][dt]];
#pragma unroll
        for (int mi = 0; mi < 4; ++mi)
          o[mi][dt] = mfma16(bv, aP[mi][ks], o[mi][dt]);
      }
    }
    // no second barrier: next iteration's barrier guarantees all waves finished
    // reading buf[cur] before any wave issues loads into it
  }

  // epilogue: normalize and store merged [B*S, D] bf16; O^T layout means each
  // lane owns q = w*64 + mi*16 + lm and 4 consecutive d per dt -> packed 8B
#pragma unroll
  for (int mi = 0; mi < 4; ++mi) {
    const float inv = __builtin_amdgcn_rcpf(lsum[mi]);
    const int gr = mq0 + w * 64 + mi * 16 + lm;
#pragma unroll
    for (int dt = 0; dt < 4; ++dt) {
      bf16x4 ov;
#pragma unroll
      for (int r = 0; r < 4; ++r) ov[r] = (__bf16)(o[mi][dt][r] * inv);
      *(bf16x4*)&Mg[(size_t)gr * DM + ch + dt * 16 + q4 * 4] = ov;
    }
  }
}

// ---------------- launch ----------------

extern "C" void kernel_launch(void* const* d_in, const int* in_sizes, int n_in,
                              void* d_out, int out_size, void* d_ws, size_t ws_size,
                              hipStream_t stream) {
  (void)in_sizes; (void)n_in; (void)out_size; (void)ws_size;
  const float* x  = (const float*)d_in[0];
  const float* Wq = (const float*)d_in[1];
  const float* Wk = (const float*)d_in[2];
  const float* Wv = (const float*)d_in[3];
  const float* fc = (const float*)d_in[4];
  float* out = (float*)d_out;

  char* base = (char*)d_ws;
  const size_t XB = (size_t)MROWS * DM * 2;  // 16 MiB
  const size_t WB = (size_t)DM * DM * 2;     // 2 MiB
  __bf16* xh  = (__bf16*)(base);
  __bf16* xl  = (__bf16*)(base + XB);
  __bf16* wqh = (__bf16*)(base + 2 * XB);
  __bf16* wql = (__bf16*)(base + 2 * XB + WB);
  __bf16* wkh = (__bf16*)(base + 2 * XB + 2 * WB);
  __bf16* wkl = (__bf16*)(base + 2 * XB + 3 * WB);
  __bf16* wvh = (__bf16*)(base + 2 * XB + 4 * WB);
  __bf16* fch = (__bf16*)(base + 2 * XB + 5 * WB);
  __bf16* Qh  = (__bf16*)(base + 2 * XB + 6 * WB);
  __bf16* Ql  = (__bf16*)(base + 3 * XB + 6 * WB);
  __bf16* Kh  = (__bf16*)(base + 4 * XB + 6 * WB);
  __bf16* Kl  = (__bf16*)(base + 5 * XB + 6 * WB);
  __bf16* Vt  = xl;  // xl dead after QK projection
  __bf16* Mg  = xh;  // xh dead after V projection

  split_x_kernel<<<dim3(8192), dim3(256), 0, stream>>>(x, xh, xl);
  wtrans4_kernel<<<dim3(4096), dim3(256), 0, stream>>>(Wq, Wk, Wv, fc,
                                                       wqh, wql, wkh, wkl, wvh, fch);

  // fused Q+K projection (Q pre-scaled by 0.125*log2(e) for base-2 flash softmax)
  gemm_qk<<<dim3(512), dim3(256), 0, stream>>>(xh, xl, wqh, wql, wkh, wkl, Qh, Ql, Kh, Kl);
  gemm_nt<3><<<dim3(512), dim3(256), 0, stream>>>(xh, wvh, (void*)Vt);

  flash_kernel<<<dim3(512), dim3(256), 0, stream>>>(Qh, Ql, Kh, Kl, Vt, Mg);

  gemm_nt<1><<<dim3(512), dim3(256), 0, stream>>>(Mg, fch, (void*)out);
}